// Round 9
// baseline (521.947 us; speedup 1.0000x reference)
//
#include <hip/hip_runtime.h>

// Round 17: ATTN STAGING DOUBLE-BUFFER (T14) — attn (105us) is staging-latency-bound:
// per-kt budget ~3900cy vs ~900cy compute; the gap is the barrier-serialized cold-HBM
// K/V fetch (qkv=40MB, not L2-resident), 2 barriers/kt, 4 blocks/CU. New schedule:
// issue async16 K(t+1) + global V(t+1) loads into the INACTIVE buffer before compute(t),
// write V regs->LDS after compute, ONE __syncthreads per kt (its implicit vmcnt/lgkm
// drain is the cross-wave handshake). LDS 33->58KB (2 blocks/CU) — latency now hidden
// by ILP instead of TLP. No arithmetic changes. All other kernels byte-identical to R16.
// Pipeline: sumsq -> GRN1 -> GEMM(qkv) -> fused flash diff-attn -> GEMM(proj)+resid+ss2
// -> GRN2 -> GEMM(ffn1)+silu -> GEMM(ffn2)+bias+resid -> f32 out.

using u16 = unsigned short;
typedef __attribute__((ext_vector_type(8))) short bh8;
typedef __attribute__((ext_vector_type(4))) float f32x4;

__device__ __forceinline__ float b2f(u16 v) { return __uint_as_float(((unsigned)v) << 16); }
__device__ __forceinline__ u16 f2b(float f) {
    unsigned u = __float_as_uint(f);
    u += 0x7fffu + ((u >> 16) & 1u);   // RNE
    return (u16)(u >> 16);
}
__device__ __forceinline__ u16 f2b_t(float f) {   // truncating pack (P-only)
    return (u16)(__float_as_uint(f) >> 16);
}
__device__ __forceinline__ void async16(const void* g, void* l) {
    __builtin_amdgcn_global_load_lds((const __attribute__((address_space(1))) void*)g,
                                     (__attribute__((address_space(3))) void*)l, 16, 0, 0);
}
__device__ __forceinline__ float ldin(const void* p, size_t i, int f32flag) {
    return f32flag ? ((const float*)p)[i] : b2f(((const u16*)p)[i]);
}
__device__ __forceinline__ float nxof(float ssv) {
    const float s = fminf(fmaxf(ssv, 1e-6f), 1000.f);
    const float gx = sqrtf(s);
    return gx / (gx + 1e-6f);
}

// ---------------- storage-mode detection (M0 bf16 / M1 f32 / M2 f32-holding-bf16) ----------------
__global__ void ndetect(const u16* __restrict__ x, int* __restrict__ flag) {
    const int t = threadIdx.x;
    int big = 0, zlo = 0;
    for (int i = t; i < 4096; i += 256) {
        const u16 w = x[i];
        big += (((w >> 7) & 0xFFu) >= 0x93u);
        if ((i & 1) == 0) zlo += (w == 0);
    }
    for (int off = 32; off; off >>= 1) {
        big += __shfl_xor(big, off);
        zlo += __shfl_xor(zlo, off);
    }
    __shared__ int wb[4], wz[4];
    if ((t & 63) == 0) { wb[t >> 6] = big; wz[t >> 6] = zlo; }
    __syncthreads();
    if (t == 0) {
        const int B = wb[0] + wb[1] + wb[2] + wb[3];
        const int Z = wz[0] + wz[1] + wz[2] + wz[3];
        *flag = (Z > 1024 || B > 64) ? 1 : 0;
    }
}

// ---------------- small vectors -> bf16 pack ----------------
__global__ void convert_small_kernel(const void* p0, const void* p1, const void* p2, const void* p3,
                                     const void* p4, const void* p5, const void* p6,
                                     const int* __restrict__ flag, u16* __restrict__ pack) {
    const int idx = blockIdx.x * 256 + threadIdx.x;
    if (idx >= 10240) return;
    const int f = *flag;
    const void* src;
    int rel;
    if (idx < 5120) {
        const int seg = idx >> 10;
        rel = idx & 1023;
        src = seg == 0 ? p0 : seg == 1 ? p1 : seg == 2 ? p2 : seg == 3 ? p3 : p4;
    } else if (idx < 9216) { src = p5; rel = idx - 5120; }
    else { src = p6; rel = idx - 9216; }
    pack[idx] = f2b(ldin(src, rel, f));
}

// ---------------- per-batch sum of squares (vectorized grid-strided + atomic) ----------------
__global__ __launch_bounds__(256) void nss(const void* __restrict__ x, const int* __restrict__ flag,
                                           float* __restrict__ ss, int mode) {
    const int b = blockIdx.y, t = threadIdx.x;
    const int f = mode ? *flag : 0;
    const size_t base = (size_t)b * 1048576;
    float acc = 0.f;
    if (f) {
        const float4* p = (const float4*)((const float*)x + base);
        for (int i = blockIdx.x * 256 + t; i < 262144; i += 64 * 256) {
            const float4 v = p[i];
            acc += v.x * v.x + v.y * v.y + v.z * v.z + v.w * v.w;
        }
    } else {
        const bh8* p = (const bh8*)((const u16*)x + base);
        for (int i = blockIdx.x * 256 + t; i < 131072; i += 64 * 256) {
            const bh8 v = p[i];
#pragma unroll
            for (int j = 0; j < 8; ++j) {
                const float xv = b2f((u16)v[j]);
                acc += xv * xv;
            }
        }
    }
    for (int off = 32; off; off >>= 1) acc += __shfl_xor(acc, off);
    __shared__ float ws4[4];
    if ((t & 63) == 0) ws4[t >> 6] = acc;
    __syncthreads();
    if (t == 0) atomicAdd(&ss[b], ws4[0] + ws4[1] + ws4[2] + ws4[3]);
}

// ---------------- GRN ----------------
__global__ __launch_bounds__(256) void grn_x_kernel(const void* __restrict__ x, const u16* __restrict__ gamma,
                                                    const u16* __restrict__ beta, const float* __restrict__ ss,
                                                    const int* __restrict__ flag, u16* __restrict__ h) {
    const size_t i0 = ((size_t)blockIdx.x * 256 + threadIdx.x) * 8;
    const int batch = (int)(i0 >> 20);
    const int dt = *flag;
    const float nx = nxof(ss[batch]);
    const int d0 = (int)(i0 & 1023);
    float xf[8];
    if (dt) {
#pragma unroll
        for (int j = 0; j < 8; ++j) xf[j] = ((const float*)x)[i0 + j];
    } else {
        const bh8 xv = *(const bh8*)((const u16*)x + i0);
#pragma unroll
        for (int j = 0; j < 8; ++j) xf[j] = b2f((u16)xv[j]);
    }
    const bh8 gv = *(const bh8*)(gamma + d0);
    const bh8 bv = *(const bh8*)(beta + d0);
    bh8 res;
#pragma unroll
    for (int j = 0; j < 8; ++j)
        res[j] = (short)f2b(b2f((u16)gv[j]) * (xf[j] * nx) + b2f((u16)bv[j]) + xf[j]);
    *(bh8*)(h + i0) = res;
}

__global__ __launch_bounds__(256) void grn_bf16_kernel(const u16* __restrict__ x, const u16* __restrict__ gamma,
                                                       const u16* __restrict__ beta, const float* __restrict__ ss,
                                                       u16* __restrict__ h) {
    const size_t i0 = ((size_t)blockIdx.x * 256 + threadIdx.x) * 8;
    const int batch = (int)(i0 >> 20);
    const float nx = nxof(ss[batch]);
    const int d0 = (int)(i0 & 1023);
    const bh8 xv = *(const bh8*)(x + i0);
    const bh8 gv = *(const bh8*)(gamma + d0);
    const bh8 bv = *(const bh8*)(beta + d0);
    bh8 res;
#pragma unroll
    for (int j = 0; j < 8; ++j) {
        const float xf = b2f((u16)xv[j]);
        res[j] = (short)f2b(b2f((u16)gv[j]) * (xf * nx) + b2f((u16)bv[j]) + xf);
    }
    *(bh8*)(h + i0) = res;
}

// ---------------- flag-aware transpose ----------------
__global__ __launch_bounds__(256) void transpose_kernel(const void* __restrict__ in, u16* __restrict__ outp,
                                                        int R, int C, const int* __restrict__ flag) {
    __shared__ u16 tile[32][33];
    const int f = *flag;
    const int cb = blockIdx.x * 32, rb = blockIdx.y * 32;
    const int tx = threadIdx.x, ty = threadIdx.y;
#pragma unroll
    for (int j = 0; j < 32; j += 8) {
        const size_t gi = (size_t)(rb + ty + j) * C + cb + tx;
        tile[ty + j][tx] = f ? f2b(((const float*)in)[gi]) : ((const u16*)in)[gi];
    }
    __syncthreads();
#pragma unroll
    for (int j = 0; j < 32; j += 8)
        outp[(size_t)(cb + ty + j) * R + rb + tx] = tile[tx][ty + j];
}

// ---------------- lambda ----------------
__global__ void lambda_kernel(const void* lq1, const void* lk1, const void* lq2, const void* lk2,
                              const int* __restrict__ flag, float* lam) {
    const int t = threadIdx.x;
    const int f = *flag;
    float a = ldin(lq1, t, f) * ldin(lk1, t, f);
    float c = ldin(lq2, t, f) * ldin(lk2, t, f);
    for (int off = 32; off; off >>= 1) { a += __shfl_xor(a, off); c += __shfl_xor(c, off); }
    if (t == 0) {
        const float l1 = fminf(fmaxf(a, -10.f), 10.f);
        const float l2 = fminf(fmaxf(c, -10.f), 10.f);
        const float lv = __expf(l1) - __expf(l2) + 0.2f;
        *lam = fminf(fmaxf(lv, 0.1f), 5.0f);
    }
}

// ---------------- fast GEMM (BK=64, swizzled K-chunks) ----------------
// LDS: As/Bs [128][64] u16. Chunk g (16B) of row r stored at slot g^(r&7) via
// pre-swizzled global source; fragment read at slot (ks*4+quad)^(col&7).
// EPI 0: out bf16 | EPI 1: bf16 = acc+bias+native-x resid, + fused ss sum-of-squares
// EPI 2: bf16 = silu(acc+bias) | EPI 3: out FLOAT32 = acc + bias + bf16 resid (final)
template <int EPI>
__global__ __launch_bounds__(256) void gemm_bt_kernel(const u16* __restrict__ A, const u16* __restrict__ Bt,
                                                      const u16* __restrict__ bias, const void* resid,
                                                      void* outp, int N, int K,
                                                      const int* __restrict__ flagp,
                                                      float* __restrict__ ssout) {
    __shared__ __attribute__((aligned(16))) u16 As[128 * 64];
    __shared__ __attribute__((aligned(16))) u16 Bs[128 * 64];
    const int tid = threadIdx.x;
    const int wave = tid >> 6, lane = tid & 63;
    const int quad = lane >> 4, col = lane & 15;
    const int wr = wave >> 1, wc = wave & 1;
    const int m0 = blockIdx.y * 128, n0 = blockIdx.x * 128;
    const int dt = (EPI == 1) ? *flagp : 0;

    // staging: lane l covers row (l>>3) of its 8-row slab, slot l&7; source chunk = (l&7)^(l>>3)
    const int srow = lane >> 3;
    const int schunk = (lane & 7) ^ srow;
    const u16* Ag = A + (size_t)(m0 + wave * 32 + srow) * K + schunk * 8;
    const u16* Bg = Bt + (size_t)(n0 + wave * 32 + srow) * K + schunk * 8;
    u16* AsW = As + (wave * 32) * 64;
    u16* BsW = Bs + (wave * 32) * 64;

    f32x4 acc[4][4];
#pragma unroll
    for (int i = 0; i < 4; ++i)
#pragma unroll
        for (int j = 0; j < 4; ++j) acc[i][j] = (f32x4){0.f, 0.f, 0.f, 0.f};

    for (int k0 = 0; k0 < K; k0 += 64) {
        __syncthreads();
#pragma unroll
        for (int it = 0; it < 4; ++it) {
            async16(Ag + k0 + (size_t)(it * 8) * K, AsW + it * 8 * 64);
            async16(Bg + k0 + (size_t)(it * 8) * K, BsW + it * 8 * 64);
        }
        __syncthreads();
#pragma unroll
        for (int ks = 0; ks < 2; ++ks) {
            const int slot = ((ks * 4 + quad) ^ (col & 7)) * 8;
            bh8 a[4], bfr[4];
#pragma unroll
            for (int i = 0; i < 4; ++i)
                a[i] = *(const bh8*)(As + (wr * 64 + i * 16 + col) * 64 + slot);
#pragma unroll
            for (int j = 0; j < 4; ++j)
                bfr[j] = *(const bh8*)(Bs + (wc * 64 + j * 16 + col) * 64 + slot);
#pragma unroll
            for (int i = 0; i < 4; ++i)
#pragma unroll
                for (int j = 0; j < 4; ++j)
                    acc[i][j] = __builtin_amdgcn_mfma_f32_16x16x32_bf16(a[i], bfr[j], acc[i][j], 0, 0, 0);
        }
    }

    float ssacc = 0.f;
#pragma unroll
    for (int i = 0; i < 4; ++i) {
        const int row0 = m0 + wr * 64 + i * 16 + quad * 4;
#pragma unroll
        for (int j = 0; j < 4; ++j) {
            const int cc = n0 + wc * 64 + j * 16 + col;
            float bb = 0.f;
            if (EPI != 0) bb = b2f(bias[cc]);
#pragma unroll
            for (int r = 0; r < 4; ++r) {
                const size_t idx = (size_t)(row0 + r) * N + cc;
                float v = acc[i][j][r];
                if (EPI == 0) {
                    ((u16*)outp)[idx] = f2b(v);
                } else if (EPI == 1) {
                    const u16 hv = f2b(v + bb + ldin(resid, idx, dt));
                    ((u16*)outp)[idx] = hv;
                    const float w = b2f(hv);
                    ssacc += w * w;                    // fused ss2 (order-only change)
                } else if (EPI == 2) {
                    v += bb;
                    ((u16*)outp)[idx] = f2b(v / (1.f + __expf(-v)));
                } else {   // EPI == 3: FINAL, float32 output
                    ((float*)outp)[idx] = v + bb + b2f(((const u16*)resid)[idx]);
                }
            }
        }
    }
    if (EPI == 1) {
        for (int off = 32; off; off >>= 1) ssacc += __shfl_xor(ssacc, off);
        __shared__ float wsum[4];
        if (lane == 0) wsum[wave] = ssacc;
        __syncthreads();
        if (tid == 0) atomicAdd(&ssout[m0 >> 10], wsum[0] + wsum[1] + wsum[2] + wsum[3]);
    }
}

// ---------------- fused differential flash attention ----------------
// Q pre-scaled by 0.125 (exact). Defer-max (T13). Lazy-l (per-lane partials).
// Clamp via v_med3_f32. P packed with TRUNCATING f2b. K/V DOUBLE-BUFFERED with
// T14 async-STAGE split: issue K(t+1) async16 + V(t+1) global loads before compute(t),
// V regs->LDS after compute, one __syncthreads per kt (implicit vmcnt/lgkm drain).
// V layout: row d (stride 72), key slot = ((key>>3) ^ (d>>3))*8 + (key&7).
// P layout: physical row psi(q) = 8*(r>>1) + 2*quad + (r&1) (stride 64),
//           block slot = (pbase ^ (psi&7))*8 + (key&7). Both bijections.
#define ATTN_L2E 1.4426950f

__device__ __forceinline__ void attn_step(bh8 qf0, bh8 qf1, const u16* __restrict__ Ks, const u16* __restrict__ Vt,
                                          u16* __restrict__ Pw, f32x4* __restrict__ O, float* __restrict__ mv,
                                          float* __restrict__ lv, int quad, int col) {
    const int sw = col & 7;
    f32x4 s[4];
#pragma unroll
    for (int nt = 0; nt < 4; ++nt) {
        const u16* kr = Ks + (nt * 16 + col) * 64;
        bh8 kb0 = *(const bh8*)(kr + ((quad ^ sw) * 8));
        bh8 kb1 = *(const bh8*)(kr + (((4 + quad) ^ sw) * 8));
        f32x4 z = (f32x4){0.f, 0.f, 0.f, 0.f};
        z = __builtin_amdgcn_mfma_f32_16x16x32_bf16(qf0, kb0, z, 0, 0, 0);
        z = __builtin_amdgcn_mfma_f32_16x16x32_bf16(qf1, kb1, z, 0, 0, 0);
        s[nt] = z;
    }
    float mx[4];
#pragma unroll
    for (int r = 0; r < 4; ++r) {
#pragma unroll
        for (int nt = 0; nt < 4; ++nt)
            s[nt][r] = __builtin_amdgcn_fmed3f(s[nt][r], -100.f, 100.f);   // clamp = median
        mx[r] = fmaxf(fmaxf(s[0][r], s[1][r]), fmaxf(s[2][r], s[3][r]));
    }
    // defer-max: full reduce + rescale only if some row max grew past threshold
    const bool ok = (mx[0] <= mv[0] + 8.f) && (mx[1] <= mv[1] + 8.f) &&
                    (mx[2] <= mv[2] + 8.f) && (mx[3] <= mv[3] + 8.f);
    if (!__all(ok)) {
#pragma unroll
        for (int off = 1; off < 16; off <<= 1)
#pragma unroll
            for (int r = 0; r < 4; ++r) mx[r] = fmaxf(mx[r], __shfl_xor(mx[r], off));
#pragma unroll
        for (int r = 0; r < 4; ++r) {
            const float mn = fmaxf(mv[r], mx[r]);
            const float alpha = __expf(mv[r] - mn);   // uniform within the 16-lane group
            mv[r] = mn;
            lv[r] *= alpha;                            // per-lane partial scales uniformly
#pragma unroll
            for (int nt = 0; nt < 4; ++nt) O[nt][r] *= alpha;
        }
    }
    float nme[4];
#pragma unroll
    for (int r = 0; r < 4; ++r) nme[r] = -mv[r] * ATTN_L2E;
    // P writes: row psi(quad*4+r), block xor psi&7 = 2*quad+(r&1)
#pragma unroll
    for (int nt = 0; nt < 4; ++nt) {
        const int key = nt * 16 + col;
        const int pbase = key >> 3;
        const int k7 = key & 7;
#pragma unroll
        for (int r = 0; r < 4; ++r) {
            const float p = __builtin_amdgcn_exp2f(__builtin_fmaf(s[nt][r], ATTN_L2E, nme[r]));
            lv[r] += p;                                // per-lane partial, no tree
            const int prow = 8 * (r >> 1) + 2 * quad + (r & 1);      // psi(q)
            const int pa = 2 * quad + (r & 1);                       // psi(q)&7
            Pw[prow * 64 + ((pbase ^ pa) * 8) + k7] = f2b_t(p);      // truncating pack
        }
    }

    // P reads: physical row psi(col), swizzle with psi(col)&7
    const int psic = 8 * ((col >> 1) & 1) + 2 * (col >> 2) + (col & 1);
    const int swp = psic & 7;
    const u16* pr = Pw + psic * 64;
    bh8 pa0 = *(const bh8*)(pr + ((quad ^ swp) * 8));
    bh8 pa1 = *(const bh8*)(pr + (((4 + quad) ^ swp) * 8));
#pragma unroll
    for (int nt = 0; nt < 4; ++nt) {
        const int fv = (2 * nt + (col >> 3)) & 7;     // V slot swizzle (= d>>3)
        const u16* vr = Vt + (nt * 16 + col) * 72;
        bh8 vb0 = *(const bh8*)(vr + ((quad ^ fv) * 8));
        bh8 vb1 = *(const bh8*)(vr + (((4 + quad) ^ fv) * 8));
        f32x4 accv = O[nt];
        accv = __builtin_amdgcn_mfma_f32_16x16x32_bf16(pa0, vb0, accv, 0, 0, 0);
        accv = __builtin_amdgcn_mfma_f32_16x16x32_bf16(pa1, vb1, accv, 0, 0, 0);
        O[nt] = accv;
    }
}

__global__ __launch_bounds__(256) void attn_kernel(const u16* __restrict__ qkv, const float* __restrict__ lam_p,
                                                   u16* __restrict__ o) {
    __shared__ __attribute__((aligned(16))) u16 K1s[2][64 * 64];
    __shared__ __attribute__((aligned(16))) u16 K2s[2][64 * 64];
    __shared__ __attribute__((aligned(16))) u16 Vt[2][64 * 72];
    __shared__ __attribute__((aligned(16))) u16 Pbuf[4][16 * 64];

    const int tid = threadIdx.x;
    const int wave = tid >> 6, lane = tid & 63;
    const int quad = lane >> 4, col = lane & 15;
    const int qb = blockIdx.x, hh = blockIdx.y, bb = blockIdx.z;

    const float lam = *lam_p;
    const int qrow = bb * 1024 + qb * 64 + wave * 16 + col;
    const u16* qp = qkv + (size_t)qrow * 5120 + hh * 64 + quad * 8;
    bh8 q1f0 = *(const bh8*)(qp);
    bh8 q1f1 = *(const bh8*)(qp + 32);
    bh8 q2f0 = *(const bh8*)(qp + 1024);
    bh8 q2f1 = *(const bh8*)(qp + 1056);
    // pre-scale Q by 0.125: exact in bf16 (pure exponent shift), scores arrive scaled
#pragma unroll
    for (int j = 0; j < 8; ++j) {
        q1f0[j] = (short)f2b(b2f((u16)q1f0[j]) * 0.125f);
        q1f1[j] = (short)f2b(b2f((u16)q1f1[j]) * 0.125f);
        q2f0[j] = (short)f2b(b2f((u16)q2f0[j]) * 0.125f);
        q2f1[j] = (short)f2b(b2f((u16)q2f1[j]) * 0.125f);
    }

    // staging lane geometry (hoisted)
    const int keyl8 = lane >> 3;                 // K: row within 8-row slab
    const int vkey = tid >> 4;                   // V: this thread's base key (per g: +16g? no, idx-based)

    f32x4 O1[4], O2[4];
    float m1v[4], l1v[4], m2v[4], l2v[4];
#pragma unroll
    for (int r = 0; r < 4; ++r) {
        O1[r] = (f32x4){0.f, 0.f, 0.f, 0.f};
        O2[r] = (f32x4){0.f, 0.f, 0.f, 0.f};
        m1v[r] = -1e30f; m2v[r] = -1e30f;
        l1v[r] = 0.f; l2v[r] = 0.f;
    }
    u16* Pw = &Pbuf[wave][0];

    // ---- staging helpers (macro-free, inlined loops) ----
    // K: issue async16 pairs for tile kt into buffer b
    // V: global ushort4 loads into regs (issue phase) / LDS writes (write phase)
    ushort4 vv[4];

    // prologue: stage kt=0 into buffer 0
    {
#pragma unroll
        for (int j = 0; j < 2; ++j) {
            const int keyl = wave * 16 + j * 8 + keyl8;
            const int chunk = (lane & 7) ^ (keyl & 7);
            const u16* kg = qkv + (size_t)(bb * 1024 + 0 * 64 + keyl) * 5120 + hh * 64 + chunk * 8;
            async16(kg + 2048, K1s[0] + (wave * 16 + j * 8) * 64);
            async16(kg + 3072, K2s[0] + (wave * 16 + j * 8) * 64);
        }
#pragma unroll
        for (int g = 0; g < 4; ++g) {
            const int idx = g * 256 + tid;
            const int key = idx >> 4;
            const int hd4 = (idx & 15) << 2;
            vv[g] = *(const ushort4*)(qkv + (size_t)(bb * 1024 + key) * 5120 + 4096 + hh * 64 + hd4);
        }
#pragma unroll
        for (int g = 0; g < 4; ++g) {
            const int idx = g * 256 + tid;
            const int key = idx >> 4;
            const int m15 = idx & 15;
            const int hd4 = m15 << 2;
            const int slot = (((key >> 3) ^ (m15 >> 1)) << 3) + (key & 7);
            Vt[0][(hd4 + 0) * 72 + slot] = vv[g].x;
            Vt[0][(hd4 + 1) * 72 + slot] = vv[g].y;
            Vt[0][(hd4 + 2) * 72 + slot] = vv[g].z;
            Vt[0][(hd4 + 3) * 72 + slot] = vv[g].w;
        }
        __syncthreads();   // drains async16 (vmcnt) + ds writes; all waves synced
    }

    int cur = 0;
    for (int kt = 0; kt < 16; ++kt) {
        const int nxt = cur ^ 1;
        if (kt < 15) {
            // issue next tile's K async16 + V global loads (land during compute below)
#pragma unroll
            for (int j = 0; j < 2; ++j) {
                const int keyl = wave * 16 + j * 8 + keyl8;
                const int chunk = (lane & 7) ^ (keyl & 7);
                const u16* kg = qkv + (size_t)(bb * 1024 + (kt + 1) * 64 + keyl) * 5120 + hh * 64 + chunk * 8;
                async16(kg + 2048, K1s[nxt] + (wave * 16 + j * 8) * 64);
                async16(kg + 3072, K2s[nxt] + (wave * 16 + j * 8) * 64);
            }
#pragma unroll
            for (int g = 0; g < 4; ++g) {
                const int idx = g * 256 + tid;
                const int key = idx >> 4;
                const int hd4 = (idx & 15) << 2;
                vv[g] = *(const ushort4*)(qkv + (size_t)(bb * 1024 + (kt + 1) * 64 + key) * 5120 + 4096 + hh * 64 + hd4);
            }
        }

        attn_step(q1f0, q1f1, K1s[cur], Vt[cur], Pw, O1, m1v, l1v, quad, col);
        attn_step(q2f0, q2f1, K2s[cur], Vt[cur], Pw, O2, m2v, l2v, quad, col);

        if (kt < 15) {
#pragma unroll
            for (int g = 0; g < 4; ++g) {
                const int idx = g * 256 + tid;
                const int key = idx >> 4;
                const int m15 = idx & 15;
                const int hd4 = m15 << 2;
                const int slot = (((key >> 3) ^ (m15 >> 1)) << 3) + (key & 7);
                Vt[nxt][(hd4 + 0) * 72 + slot] = vv[g].x;
                Vt[nxt][(hd4 + 1) * 72 + slot] = vv[g].y;
                Vt[nxt][(hd4 + 2) * 72 + slot] = vv[g].z;
                Vt[nxt][(hd4 + 3) * 72 + slot] = vv[g].w;
            }
        }
        __syncthreads();   // drain staging (vmcnt+lgkm) across waves; cur reads complete
        cur = nxt;
    }

    // single end-of-kernel cross-lane reduce of the per-lane l partials
#pragma unroll
    for (int off = 1; off < 16; off <<= 1)
#pragma unroll
        for (int r = 0; r < 4; ++r) {
            l1v[r] += __shfl_xor(l1v[r], off);
            l2v[r] += __shfl_xor(l2v[r], off);
        }

    float w1v[4], w2v[4];
#pragma unroll
    for (int r = 0; r < 4; ++r) {
        w1v[r] = 1.f / (l1v[r] + 1e-6f);
        w2v[r] = lam / (l2v[r] + 1e-6f);
    }
    const size_t orow0 = (size_t)(bb * 1024 + qb * 64 + wave * 16 + quad * 4);
#pragma unroll
    for (int nt = 0; nt < 4; ++nt) {
        const int cc = hh * 64 + nt * 16 + col;
#pragma unroll
        for (int r = 0; r < 4; ++r)
            o[(orow0 + r) * 1024 + cc] = f2b(O1[nt][r] * w1v[r] - O2[nt][r] * w2v[r]);
    }
}

// ---- host-contract sentinel (f32 out) ----
__global__ void nsentinel(float* __restrict__ outp, int hc) {
    const size_t i0 = ((size_t)blockIdx.x * 256 + threadIdx.x) * 4;
    const float v = 1.0e6f * (float)(1 + hc);
#pragma unroll
    for (int j = 0; j < 4; ++j) outp[i0 + j] = v;
}

// ---------------- launcher ----------------
extern "C" void kernel_launch(void* const* d_in, const int* in_sizes, int n_in,
                              void* d_out, int out_size, void* d_ws, size_t ws_size,
                              hipStream_t stream) {
    const size_t MB = 1ull << 20;
    static const int exp_sizes[16] = {4194304, 5242880, 64, 64, 64, 64, 1048576, 1024,
                                      1024, 1024, 1024, 1024, 4194304, 4096, 4194304, 1024};
    int hc = 0;
    if (n_in != 16) hc = 1;
    else {
        for (int i = 0; i < 16; ++i)
            if (in_sizes[i] != exp_sizes[i]) { hc = 2; break; }
    }
    if (hc == 0 && out_size != 4194304) hc = 3;
    if (hc == 0 && ws_size < 0x10000 + 58 * MB) hc = 4;
    if (hc) {
        nsentinel<<<4096, 256, 0, stream>>>((float*)d_out, hc);
        return;
    }

    const void* x      = d_in[0];
    const void* w_qkv  = d_in[1];
    const void* lq1    = d_in[2];
    const void* lk1    = d_in[3];
    const void* lq2    = d_in[4];
    const void* lk2    = d_in[5];
    const void* w_proj = d_in[6];
    const void* b_proj = d_in[7];
    const void* gamma1 = d_in[8];
    const void* beta1  = d_in[9];
    const void* gamma2 = d_in[10];
    const void* beta2  = d_in[11];
    const void* w1     = d_in[12];
    const void* b1     = d_in[13];
    const void* w2     = d_in[14];
    const void* b2     = d_in[15];
    char* ws = (char*)d_ws;

    float* ss1  = (float*)(ws + 0);
    float* ss2  = (float*)(ws + 16);
    float* lamp = (float*)(ws + 32);
    int*   flag = (int*)(ws + 36);
    u16* pack = (u16*)(ws + 4096);
    u16* bprojp = pack;
    u16* g1p = pack + 1024;
    u16* be1p = pack + 2048;
    u16* g2p = pack + 3072;
    u16* be2p = pack + 4096;
    u16* b1p = pack + 5120;
    u16* b2p = pack + 9216;

    // ws region plan (58MB + 64KB), phase-exact liveness:
    char* base = ws + 0x10000;
    u16* Fqkv  = (u16*)(base);             // [0,40)  qkv ; later Fmid in [0,32)
    u16* Fmid  = (u16*)(base);
    u16* FwT   = (u16*)(base + 32 * MB);   // [32,40) w1T then w2T (after attn consumed qkv)
    u16* FqkvT = (u16*)(base + 40 * MB);   // [40,50) wqkvT
    u16* FX2   = (u16*)(base + 40 * MB);   // [40,48) X2 (after wqkvT dead)
    u16* FpT   = (u16*)(base + 48 * MB);   // [48,50) wprojT (after wqkvT dead)
    u16* Fc    = (u16*)(base + 50 * MB);   // [50,58) hbuf -> obuf -> h2

    hipMemsetAsync(ws, 0, 128, stream);
    ndetect<<<1, 256, 0, stream>>>((const u16*)x, flag);
    convert_small_kernel<<<40, 256, 0, stream>>>(b_proj, gamma1, beta1, gamma2, beta2, b1, b2, flag, pack);
    lambda_kernel<<<1, 64, 0, stream>>>(lq1, lk1, lq2, lk2, flag, lamp);
    nss<<<dim3(64, 4), 256, 0, stream>>>(x, flag, ss1, 1);

    grn_x_kernel<<<2048, 256, 0, stream>>>(x, g1p, be1p, ss1, flag, Fc);
    transpose_kernel<<<dim3(160, 32), dim3(32, 8), 0, stream>>>(w_qkv, FqkvT, 1024, 5120, flag);
    gemm_bt_kernel<0><<<dim3(40, 32), 256, 0, stream>>>(Fc, FqkvT, nullptr, nullptr, Fqkv, 5120, 1024, flag, nullptr);
    attn_kernel<<<dim3(16, 16, 4), 256, 0, stream>>>(Fqkv, lamp, Fc);
    transpose_kernel<<<dim3(32, 32), dim3(32, 8), 0, stream>>>(w_proj, FpT, 1024, 1024, flag);
    gemm_bt_kernel<1><<<dim3(8, 32), 256, 0, stream>>>(Fc, FpT, bprojp, x, FX2, 1024, 1024, flag, ss2);
    grn_bf16_kernel<<<2048, 256, 0, stream>>>(FX2, g2p, be2p, ss2, Fc);
    transpose_kernel<<<dim3(128, 32), dim3(32, 8), 0, stream>>>(w1, FwT, 1024, 4096, flag);
    gemm_bt_kernel<2><<<dim3(32, 32), 256, 0, stream>>>(Fc, FwT, b1p, nullptr, Fmid, 4096, 1024, flag, nullptr);
    transpose_kernel<<<dim3(32, 128), dim3(32, 8), 0, stream>>>(w2, FwT, 4096, 1024, flag);
    gemm_bt_kernel<3><<<dim3(8, 32), 256, 0, stream>>>(Fmid, FwT, b2p, FX2, d_out, 1024, 4096, flag, nullptr);
}

// Round 10
// 476.177 us; speedup vs baseline: 1.0961x; 1.0961x over previous
//
#include <hip/hip_runtime.h>

// Round 18: REVERT attn double-buffer (R17 regressed 105->146us: 2 blocks/CU lost the
// cross-block TLP that was hiding staging latency; lesson: occupancy > in-block ILP
// here). attn restored byte-exact to R16 (480us config). NEW: BM=64 GEMM tile variant
// for the two grid-limited GEMMs — proj (EPI1) and ffn2 (EPI3) ran 256 blocks = 1
// block/CU (zero cross-block overlap). 64x128 tile, 4 waves of 32x64, grid 8x64=512
// = 2 blocks/CU, LDS 24KB, same swizzle algebra / K-order -> bit-identical output.
// Pipeline: sumsq -> GRN1 -> GEMM(qkv) -> fused flash diff-attn -> GEMM(proj)+resid+ss2
// -> GRN2 -> GEMM(ffn1)+silu -> GEMM(ffn2)+bias+resid -> f32 out.

using u16 = unsigned short;
typedef __attribute__((ext_vector_type(8))) short bh8;
typedef __attribute__((ext_vector_type(4))) float f32x4;

__device__ __forceinline__ float b2f(u16 v) { return __uint_as_float(((unsigned)v) << 16); }
__device__ __forceinline__ u16 f2b(float f) {
    unsigned u = __float_as_uint(f);
    u += 0x7fffu + ((u >> 16) & 1u);   // RNE
    return (u16)(u >> 16);
}
__device__ __forceinline__ u16 f2b_t(float f) {   // truncating pack (P-only)
    return (u16)(__float_as_uint(f) >> 16);
}
__device__ __forceinline__ void async16(const void* g, void* l) {
    __builtin_amdgcn_global_load_lds((const __attribute__((address_space(1))) void*)g,
                                     (__attribute__((address_space(3))) void*)l, 16, 0, 0);
}
__device__ __forceinline__ float ldin(const void* p, size_t i, int f32flag) {
    return f32flag ? ((const float*)p)[i] : b2f(((const u16*)p)[i]);
}
__device__ __forceinline__ float nxof(float ssv) {
    const float s = fminf(fmaxf(ssv, 1e-6f), 1000.f);
    const float gx = sqrtf(s);
    return gx / (gx + 1e-6f);
}

// ---------------- storage-mode detection (M0 bf16 / M1 f32 / M2 f32-holding-bf16) ----------------
__global__ void ndetect(const u16* __restrict__ x, int* __restrict__ flag) {
    const int t = threadIdx.x;
    int big = 0, zlo = 0;
    for (int i = t; i < 4096; i += 256) {
        const u16 w = x[i];
        big += (((w >> 7) & 0xFFu) >= 0x93u);
        if ((i & 1) == 0) zlo += (w == 0);
    }
    for (int off = 32; off; off >>= 1) {
        big += __shfl_xor(big, off);
        zlo += __shfl_xor(zlo, off);
    }
    __shared__ int wb[4], wz[4];
    if ((t & 63) == 0) { wb[t >> 6] = big; wz[t >> 6] = zlo; }
    __syncthreads();
    if (t == 0) {
        const int B = wb[0] + wb[1] + wb[2] + wb[3];
        const int Z = wz[0] + wz[1] + wz[2] + wz[3];
        *flag = (Z > 1024 || B > 64) ? 1 : 0;
    }
}

// ---------------- small vectors -> bf16 pack ----------------
__global__ void convert_small_kernel(const void* p0, const void* p1, const void* p2, const void* p3,
                                     const void* p4, const void* p5, const void* p6,
                                     const int* __restrict__ flag, u16* __restrict__ pack) {
    const int idx = blockIdx.x * 256 + threadIdx.x;
    if (idx >= 10240) return;
    const int f = *flag;
    const void* src;
    int rel;
    if (idx < 5120) {
        const int seg = idx >> 10;
        rel = idx & 1023;
        src = seg == 0 ? p0 : seg == 1 ? p1 : seg == 2 ? p2 : seg == 3 ? p3 : p4;
    } else if (idx < 9216) { src = p5; rel = idx - 5120; }
    else { src = p6; rel = idx - 9216; }
    pack[idx] = f2b(ldin(src, rel, f));
}

// ---------------- per-batch sum of squares (vectorized grid-strided + atomic) ----------------
__global__ __launch_bounds__(256) void nss(const void* __restrict__ x, const int* __restrict__ flag,
                                           float* __restrict__ ss, int mode) {
    const int b = blockIdx.y, t = threadIdx.x;
    const int f = mode ? *flag : 0;
    const size_t base = (size_t)b * 1048576;
    float acc = 0.f;
    if (f) {
        const float4* p = (const float4*)((const float*)x + base);
        for (int i = blockIdx.x * 256 + t; i < 262144; i += 64 * 256) {
            const float4 v = p[i];
            acc += v.x * v.x + v.y * v.y + v.z * v.z + v.w * v.w;
        }
    } else {
        const bh8* p = (const bh8*)((const u16*)x + base);
        for (int i = blockIdx.x * 256 + t; i < 131072; i += 64 * 256) {
            const bh8 v = p[i];
#pragma unroll
            for (int j = 0; j < 8; ++j) {
                const float xv = b2f((u16)v[j]);
                acc += xv * xv;
            }
        }
    }
    for (int off = 32; off; off >>= 1) acc += __shfl_xor(acc, off);
    __shared__ float ws4[4];
    if ((t & 63) == 0) ws4[t >> 6] = acc;
    __syncthreads();
    if (t == 0) atomicAdd(&ss[b], ws4[0] + ws4[1] + ws4[2] + ws4[3]);
}

// ---------------- GRN ----------------
__global__ __launch_bounds__(256) void grn_x_kernel(const void* __restrict__ x, const u16* __restrict__ gamma,
                                                    const u16* __restrict__ beta, const float* __restrict__ ss,
                                                    const int* __restrict__ flag, u16* __restrict__ h) {
    const size_t i0 = ((size_t)blockIdx.x * 256 + threadIdx.x) * 8;
    const int batch = (int)(i0 >> 20);
    const int dt = *flag;
    const float nx = nxof(ss[batch]);
    const int d0 = (int)(i0 & 1023);
    float xf[8];
    if (dt) {
#pragma unroll
        for (int j = 0; j < 8; ++j) xf[j] = ((const float*)x)[i0 + j];
    } else {
        const bh8 xv = *(const bh8*)((const u16*)x + i0);
#pragma unroll
        for (int j = 0; j < 8; ++j) xf[j] = b2f((u16)xv[j]);
    }
    const bh8 gv = *(const bh8*)(gamma + d0);
    const bh8 bv = *(const bh8*)(beta + d0);
    bh8 res;
#pragma unroll
    for (int j = 0; j < 8; ++j)
        res[j] = (short)f2b(b2f((u16)gv[j]) * (xf[j] * nx) + b2f((u16)bv[j]) + xf[j]);
    *(bh8*)(h + i0) = res;
}

__global__ __launch_bounds__(256) void grn_bf16_kernel(const u16* __restrict__ x, const u16* __restrict__ gamma,
                                                       const u16* __restrict__ beta, const float* __restrict__ ss,
                                                       u16* __restrict__ h) {
    const size_t i0 = ((size_t)blockIdx.x * 256 + threadIdx.x) * 8;
    const int batch = (int)(i0 >> 20);
    const float nx = nxof(ss[batch]);
    const int d0 = (int)(i0 & 1023);
    const bh8 xv = *(const bh8*)(x + i0);
    const bh8 gv = *(const bh8*)(gamma + d0);
    const bh8 bv = *(const bh8*)(beta + d0);
    bh8 res;
#pragma unroll
    for (int j = 0; j < 8; ++j) {
        const float xf = b2f((u16)xv[j]);
        res[j] = (short)f2b(b2f((u16)gv[j]) * (xf * nx) + b2f((u16)bv[j]) + xf);
    }
    *(bh8*)(h + i0) = res;
}

// ---------------- flag-aware transpose ----------------
__global__ __launch_bounds__(256) void transpose_kernel(const void* __restrict__ in, u16* __restrict__ outp,
                                                        int R, int C, const int* __restrict__ flag) {
    __shared__ u16 tile[32][33];
    const int f = *flag;
    const int cb = blockIdx.x * 32, rb = blockIdx.y * 32;
    const int tx = threadIdx.x, ty = threadIdx.y;
#pragma unroll
    for (int j = 0; j < 32; j += 8) {
        const size_t gi = (size_t)(rb + ty + j) * C + cb + tx;
        tile[ty + j][tx] = f ? f2b(((const float*)in)[gi]) : ((const u16*)in)[gi];
    }
    __syncthreads();
#pragma unroll
    for (int j = 0; j < 32; j += 8)
        outp[(size_t)(cb + ty + j) * R + rb + tx] = tile[tx][ty + j];
}

// ---------------- lambda ----------------
__global__ void lambda_kernel(const void* lq1, const void* lk1, const void* lq2, const void* lk2,
                              const int* __restrict__ flag, float* lam) {
    const int t = threadIdx.x;
    const int f = *flag;
    float a = ldin(lq1, t, f) * ldin(lk1, t, f);
    float c = ldin(lq2, t, f) * ldin(lk2, t, f);
    for (int off = 32; off; off >>= 1) { a += __shfl_xor(a, off); c += __shfl_xor(c, off); }
    if (t == 0) {
        const float l1 = fminf(fmaxf(a, -10.f), 10.f);
        const float l2 = fminf(fmaxf(c, -10.f), 10.f);
        const float lv = __expf(l1) - __expf(l2) + 0.2f;
        *lam = fminf(fmaxf(lv, 0.1f), 5.0f);
    }
}

// ---------------- fast GEMM (BK=64, swizzled K-chunks; BM templated) ----------------
// LDS: As[BM][64] / Bs[128][64] u16. Chunk g (16B) of row r stored at slot g^(r&7)
// via pre-swizzled global source; fragment read at slot (ks*4+quad)^(col&7).
// BM=128: 4 waves of 64x64 (acc[4][4]). BM=64: 4 waves of 32x64 (acc[2][4]),
// grid doubles -> 2 blocks/CU for the formerly grid-limited proj/ffn2 GEMMs.
// EPI 0: out bf16 | EPI 1: bf16 = acc+bias+native-x resid, + fused ss sum-of-squares
// EPI 2: bf16 = silu(acc+bias) | EPI 3: out FLOAT32 = acc + bias + bf16 resid (final)
template <int EPI, int BM>
__global__ __launch_bounds__(256) void gemm_bt_kernel(const u16* __restrict__ A, const u16* __restrict__ Bt,
                                                      const u16* __restrict__ bias, const void* resid,
                                                      void* outp, int N, int K,
                                                      const int* __restrict__ flagp,
                                                      float* __restrict__ ssout) {
    constexpr int MI = BM / 32;        // M-fragments per wave (4 or 2)
    constexpr int AR = BM / 4;         // A rows staged per wave (32 or 16)
    __shared__ __attribute__((aligned(16))) u16 As[BM * 64];
    __shared__ __attribute__((aligned(16))) u16 Bs[128 * 64];
    const int tid = threadIdx.x;
    const int wave = tid >> 6, lane = tid & 63;
    const int quad = lane >> 4, col = lane & 15;
    const int wr = wave >> 1, wc = wave & 1;
    const int m0 = blockIdx.y * BM, n0 = blockIdx.x * 128;
    const int dt = (EPI == 1) ? *flagp : 0;

    // staging: lane l covers row (l>>3) of each 8-row slab, slot l&7; source chunk = (l&7)^(l>>3)
    const int srow = lane >> 3;
    const int schunk = (lane & 7) ^ srow;
    const u16* Ag = A + (size_t)(m0 + wave * AR + srow) * K + schunk * 8;
    const u16* Bg = Bt + (size_t)(n0 + wave * 32 + srow) * K + schunk * 8;
    u16* AsW = As + (wave * AR) * 64;
    u16* BsW = Bs + (wave * 32) * 64;

    f32x4 acc[MI][4];
#pragma unroll
    for (int i = 0; i < MI; ++i)
#pragma unroll
        for (int j = 0; j < 4; ++j) acc[i][j] = (f32x4){0.f, 0.f, 0.f, 0.f};

    for (int k0 = 0; k0 < K; k0 += 64) {
        __syncthreads();
#pragma unroll
        for (int it = 0; it < MI; ++it)
            async16(Ag + k0 + (size_t)(it * 8) * K, AsW + it * 8 * 64);
#pragma unroll
        for (int it = 0; it < 4; ++it)
            async16(Bg + k0 + (size_t)(it * 8) * K, BsW + it * 8 * 64);
        __syncthreads();
#pragma unroll
        for (int ks = 0; ks < 2; ++ks) {
            const int slot = ((ks * 4 + quad) ^ (col & 7)) * 8;
            bh8 a[MI], bfr[4];
#pragma unroll
            for (int i = 0; i < MI; ++i)
                a[i] = *(const bh8*)(As + (wr * (BM / 2) + i * 16 + col) * 64 + slot);
#pragma unroll
            for (int j = 0; j < 4; ++j)
                bfr[j] = *(const bh8*)(Bs + (wc * 64 + j * 16 + col) * 64 + slot);
#pragma unroll
            for (int i = 0; i < MI; ++i)
#pragma unroll
                for (int j = 0; j < 4; ++j)
                    acc[i][j] = __builtin_amdgcn_mfma_f32_16x16x32_bf16(a[i], bfr[j], acc[i][j], 0, 0, 0);
        }
    }

    float ssacc = 0.f;
#pragma unroll
    for (int i = 0; i < MI; ++i) {
        const int row0 = m0 + wr * (BM / 2) + i * 16 + quad * 4;
#pragma unroll
        for (int j = 0; j < 4; ++j) {
            const int cc = n0 + wc * 64 + j * 16 + col;
            float bb = 0.f;
            if (EPI != 0) bb = b2f(bias[cc]);
#pragma unroll
            for (int r = 0; r < 4; ++r) {
                const size_t idx = (size_t)(row0 + r) * N + cc;
                float v = acc[i][j][r];
                if (EPI == 0) {
                    ((u16*)outp)[idx] = f2b(v);
                } else if (EPI == 1) {
                    const u16 hv = f2b(v + bb + ldin(resid, idx, dt));
                    ((u16*)outp)[idx] = hv;
                    const float w = b2f(hv);
                    ssacc += w * w;                    // fused ss2 (order-only change)
                } else if (EPI == 2) {
                    v += bb;
                    ((u16*)outp)[idx] = f2b(v / (1.f + __expf(-v)));
                } else {   // EPI == 3: FINAL, float32 output
                    ((float*)outp)[idx] = v + bb + b2f(((const u16*)resid)[idx]);
                }
            }
        }
    }
    if (EPI == 1) {
        for (int off = 32; off; off >>= 1) ssacc += __shfl_xor(ssacc, off);
        __shared__ float wsum[4];
        if (lane == 0) wsum[wave] = ssacc;
        __syncthreads();
        if (tid == 0) atomicAdd(&ssout[m0 >> 10], wsum[0] + wsum[1] + wsum[2] + wsum[3]);
    }
}

// ---------------- fused differential flash attention (R16 config, reverted) ----------------
// Q pre-scaled by 0.125 (exact). Defer-max (T13). Lazy-l (per-lane partials).
// Clamp via v_med3_f32. P packed with TRUNCATING f2b. Single-buffered staging
// (R17's double-buffer regressed: occupancy 4->2 blocks/CU lost cross-block TLP).
// V layout: row d (stride 72), key slot = ((key>>3) ^ (d>>3))*8 + (key&7).
// P layout: physical row psi(q) = 8*(r>>1) + 2*quad + (r&1) (stride 64),
//           block slot = (pbase ^ (psi&7))*8 + (key&7). Both bijections.
#define ATTN_L2E 1.4426950f

__device__ __forceinline__ void attn_step(bh8 qf0, bh8 qf1, const u16* __restrict__ Ks, const u16* __restrict__ Vt,
                                          u16* __restrict__ Pw, f32x4* __restrict__ O, float* __restrict__ mv,
                                          float* __restrict__ lv, int quad, int col) {
    const int sw = col & 7;
    f32x4 s[4];
#pragma unroll
    for (int nt = 0; nt < 4; ++nt) {
        const u16* kr = Ks + (nt * 16 + col) * 64;
        bh8 kb0 = *(const bh8*)(kr + ((quad ^ sw) * 8));
        bh8 kb1 = *(const bh8*)(kr + (((4 + quad) ^ sw) * 8));
        f32x4 z = (f32x4){0.f, 0.f, 0.f, 0.f};
        z = __builtin_amdgcn_mfma_f32_16x16x32_bf16(qf0, kb0, z, 0, 0, 0);
        z = __builtin_amdgcn_mfma_f32_16x16x32_bf16(qf1, kb1, z, 0, 0, 0);
        s[nt] = z;
    }
    float mx[4];
#pragma unroll
    for (int r = 0; r < 4; ++r) {
#pragma unroll
        for (int nt = 0; nt < 4; ++nt)
            s[nt][r] = __builtin_amdgcn_fmed3f(s[nt][r], -100.f, 100.f);   // clamp = median
        mx[r] = fmaxf(fmaxf(s[0][r], s[1][r]), fmaxf(s[2][r], s[3][r]));
    }
    // defer-max: full reduce + rescale only if some row max grew past threshold
    const bool ok = (mx[0] <= mv[0] + 8.f) && (mx[1] <= mv[1] + 8.f) &&
                    (mx[2] <= mv[2] + 8.f) && (mx[3] <= mv[3] + 8.f);
    if (!__all(ok)) {
#pragma unroll
        for (int off = 1; off < 16; off <<= 1)
#pragma unroll
            for (int r = 0; r < 4; ++r) mx[r] = fmaxf(mx[r], __shfl_xor(mx[r], off));
#pragma unroll
        for (int r = 0; r < 4; ++r) {
            const float mn = fmaxf(mv[r], mx[r]);
            const float alpha = __expf(mv[r] - mn);   // uniform within the 16-lane group
            mv[r] = mn;
            lv[r] *= alpha;                            // per-lane partial scales uniformly
#pragma unroll
            for (int nt = 0; nt < 4; ++nt) O[nt][r] *= alpha;
        }
    }
    float nme[4];
#pragma unroll
    for (int r = 0; r < 4; ++r) nme[r] = -mv[r] * ATTN_L2E;
    // P writes: row psi(quad*4+r), block xor psi&7 = 2*quad+(r&1)
#pragma unroll
    for (int nt = 0; nt < 4; ++nt) {
        const int key = nt * 16 + col;
        const int pbase = key >> 3;
        const int k7 = key & 7;
#pragma unroll
        for (int r = 0; r < 4; ++r) {
            const float p = __builtin_amdgcn_exp2f(__builtin_fmaf(s[nt][r], ATTN_L2E, nme[r]));
            lv[r] += p;                                // per-lane partial, no tree
            const int prow = 8 * (r >> 1) + 2 * quad + (r & 1);      // psi(q)
            const int pa = 2 * quad + (r & 1);                       // psi(q)&7
            Pw[prow * 64 + ((pbase ^ pa) * 8) + k7] = f2b_t(p);      // truncating pack
        }
    }

    // P reads: physical row psi(col), swizzle with psi(col)&7
    const int psic = 8 * ((col >> 1) & 1) + 2 * (col >> 2) + (col & 1);
    const int swp = psic & 7;
    const u16* pr = Pw + psic * 64;
    bh8 pa0 = *(const bh8*)(pr + ((quad ^ swp) * 8));
    bh8 pa1 = *(const bh8*)(pr + (((4 + quad) ^ swp) * 8));
#pragma unroll
    for (int nt = 0; nt < 4; ++nt) {
        const int fv = (2 * nt + (col >> 3)) & 7;     // V slot swizzle (= d>>3)
        const u16* vr = Vt + (nt * 16 + col) * 72;
        bh8 vb0 = *(const bh8*)(vr + ((quad ^ fv) * 8));
        bh8 vb1 = *(const bh8*)(vr + (((4 + quad) ^ fv) * 8));
        f32x4 accv = O[nt];
        accv = __builtin_amdgcn_mfma_f32_16x16x32_bf16(pa0, vb0, accv, 0, 0, 0);
        accv = __builtin_amdgcn_mfma_f32_16x16x32_bf16(pa1, vb1, accv, 0, 0, 0);
        O[nt] = accv;
    }
}

__global__ __launch_bounds__(256) void attn_kernel(const u16* __restrict__ qkv, const float* __restrict__ lam_p,
                                                   u16* __restrict__ o) {
    __shared__ __attribute__((aligned(16))) u16 K1s[64 * 64];
    __shared__ __attribute__((aligned(16))) u16 K2s[64 * 64];
    __shared__ __attribute__((aligned(16))) u16 Vt[64 * 72];
    __shared__ __attribute__((aligned(16))) u16 Pbuf[4][16 * 64];

    const int tid = threadIdx.x;
    const int wave = tid >> 6, lane = tid & 63;
    const int quad = lane >> 4, col = lane & 15;
    const int qb = blockIdx.x, hh = blockIdx.y, bb = blockIdx.z;

    const float lam = *lam_p;
    const int qrow = bb * 1024 + qb * 64 + wave * 16 + col;
    const u16* qp = qkv + (size_t)qrow * 5120 + hh * 64 + quad * 8;
    bh8 q1f0 = *(const bh8*)(qp);
    bh8 q1f1 = *(const bh8*)(qp + 32);
    bh8 q2f0 = *(const bh8*)(qp + 1024);
    bh8 q2f1 = *(const bh8*)(qp + 1056);
    // pre-scale Q by 0.125: exact in bf16 (pure exponent shift), scores arrive scaled
#pragma unroll
    for (int j = 0; j < 8; ++j) {
        q1f0[j] = (short)f2b(b2f((u16)q1f0[j]) * 0.125f);
        q1f1[j] = (short)f2b(b2f((u16)q1f1[j]) * 0.125f);
        q2f0[j] = (short)f2b(b2f((u16)q2f0[j]) * 0.125f);
        q2f1[j] = (short)f2b(b2f((u16)q2f1[j]) * 0.125f);
    }

    f32x4 O1[4], O2[4];
    float m1v[4], l1v[4], m2v[4], l2v[4];
#pragma unroll
    for (int r = 0; r < 4; ++r) {
        O1[r] = (f32x4){0.f, 0.f, 0.f, 0.f};
        O2[r] = (f32x4){0.f, 0.f, 0.f, 0.f};
        m1v[r] = -1e30f; m2v[r] = -1e30f;
        l1v[r] = 0.f; l2v[r] = 0.f;
    }
    u16* Pw = &Pbuf[wave][0];

    for (int kt = 0; kt < 16; ++kt) {
        __syncthreads();
#pragma unroll
        for (int j = 0; j < 2; ++j) {
            const int keyl = wave * 16 + j * 8 + (lane >> 3);
            const int chunk = (lane & 7) ^ (keyl & 7);
            const u16* kg = qkv + (size_t)(bb * 1024 + kt * 64 + keyl) * 5120 + hh * 64 + chunk * 8;
            async16(kg + 2048, K1s + (wave * 16 + j * 8) * 64);
            async16(kg + 3072, K2s + (wave * 16 + j * 8) * 64);
        }
#pragma unroll
        for (int g = 0; g < 4; ++g) {
            const int idx = g * 256 + tid;
            const int key = idx >> 4;
            const int m15 = idx & 15;
            const int hd4 = m15 << 2;
            // V slot swizzle: slot = ((key>>3) ^ (d>>3))*8 + (key&7); d>>3 = m15>>1 for all 4 rows
            const int slot = (((key >> 3) ^ (m15 >> 1)) << 3) + (key & 7);
            const u16* vp = qkv + (size_t)(bb * 1024 + kt * 64 + key) * 5120 + 4096 + hh * 64 + hd4;
            const ushort4 vv = *(const ushort4*)vp;
            Vt[(hd4 + 0) * 72 + slot] = vv.x;
            Vt[(hd4 + 1) * 72 + slot] = vv.y;
            Vt[(hd4 + 2) * 72 + slot] = vv.z;
            Vt[(hd4 + 3) * 72 + slot] = vv.w;
        }
        __syncthreads();

        attn_step(q1f0, q1f1, K1s, Vt, Pw, O1, m1v, l1v, quad, col);
        attn_step(q2f0, q2f1, K2s, Vt, Pw, O2, m2v, l2v, quad, col);
    }

    // single end-of-kernel cross-lane reduce of the per-lane l partials
#pragma unroll
    for (int off = 1; off < 16; off <<= 1)
#pragma unroll
        for (int r = 0; r < 4; ++r) {
            l1v[r] += __shfl_xor(l1v[r], off);
            l2v[r] += __shfl_xor(l2v[r], off);
        }

    float w1v[4], w2v[4];
#pragma unroll
    for (int r = 0; r < 4; ++r) {
        w1v[r] = 1.f / (l1v[r] + 1e-6f);
        w2v[r] = lam / (l2v[r] + 1e-6f);
    }
    const size_t orow0 = (size_t)(bb * 1024 + qb * 64 + wave * 16 + quad * 4);
#pragma unroll
    for (int nt = 0; nt < 4; ++nt) {
        const int cc = hh * 64 + nt * 16 + col;
#pragma unroll
        for (int r = 0; r < 4; ++r)
            o[(orow0 + r) * 1024 + cc] = f2b(O1[nt][r] * w1v[r] - O2[nt][r] * w2v[r]);
    }
}

// ---- host-contract sentinel (f32 out) ----
__global__ void nsentinel(float* __restrict__ outp, int hc) {
    const size_t i0 = ((size_t)blockIdx.x * 256 + threadIdx.x) * 4;
    const float v = 1.0e6f * (float)(1 + hc);
#pragma unroll
    for (int j = 0; j < 4; ++j) outp[i0 + j] = v;
}

// ---------------- launcher ----------------
extern "C" void kernel_launch(void* const* d_in, const int* in_sizes, int n_in,
                              void* d_out, int out_size, void* d_ws, size_t ws_size,
                              hipStream_t stream) {
    const size_t MB = 1ull << 20;
    static const int exp_sizes[16] = {4194304, 5242880, 64, 64, 64, 64, 1048576, 1024,
                                      1024, 1024, 1024, 1024, 4194304, 4096, 4194304, 1024};
    int hc = 0;
    if (n_in != 16) hc = 1;
    else {
        for (int i = 0; i < 16; ++i)
            if (in_sizes[i] != exp_sizes[i]) { hc = 2; break; }
    }
    if (hc == 0 && out_size != 4194304) hc = 3;
    if (hc == 0 && ws_size < 0x10000 + 58 * MB) hc = 4;
    if (hc) {
        nsentinel<<<4096, 256, 0, stream>>>((float*)d_out, hc);
        return;
    }

    const void* x      = d_in[0];
    const void* w_qkv  = d_in[1];
    const void* lq1    = d_in[2];
    const void* lk1    = d_in[3];
    const void* lq2    = d_in[4];
    const void* lk2    = d_in[5];
    const void* w_proj = d_in[6];
    const void* b_proj = d_in[7];
    const void* gamma1 = d_in[8];
    const void* beta1  = d_in[9];
    const void* gamma2 = d_in[10];
    const void* beta2  = d_in[11];
    const void* w1     = d_in[12];
    const void* b1     = d_in[13];
    const void* w2     = d_in[14];
    const void* b2     = d_in[15];
    char* ws = (char*)d_ws;

    float* ss1  = (float*)(ws + 0);
    float* ss2  = (float*)(ws + 16);
    float* lamp = (float*)(ws + 32);
    int*   flag = (int*)(ws + 36);
    u16* pack = (u16*)(ws + 4096);
    u16* bprojp = pack;
    u16* g1p = pack + 1024;
    u16* be1p = pack + 2048;
    u16* g2p = pack + 3072;
    u16* be2p = pack + 4096;
    u16* b1p = pack + 5120;
    u16* b2p = pack + 9216;

    // ws region plan (58MB + 64KB), phase-exact liveness:
    char* base = ws + 0x10000;
    u16* Fqkv  = (u16*)(base);             // [0,40)  qkv ; later Fmid in [0,32)
    u16* Fmid  = (u16*)(base);
    u16* FwT   = (u16*)(base + 32 * MB);   // [32,40) w1T then w2T (after attn consumed qkv)
    u16* FqkvT = (u16*)(base + 40 * MB);   // [40,50) wqkvT
    u16* FX2   = (u16*)(base + 40 * MB);   // [40,48) X2 (after wqkvT dead)
    u16* FpT   = (u16*)(base + 48 * MB);   // [48,50) wprojT (after wqkvT dead)
    u16* Fc    = (u16*)(base + 50 * MB);   // [50,58) hbuf -> obuf -> h2

    hipMemsetAsync(ws, 0, 128, stream);
    ndetect<<<1, 256, 0, stream>>>((const u16*)x, flag);
    convert_small_kernel<<<40, 256, 0, stream>>>(b_proj, gamma1, beta1, gamma2, beta2, b1, b2, flag, pack);
    lambda_kernel<<<1, 64, 0, stream>>>(lq1, lk1, lq2, lk2, flag, lamp);
    nss<<<dim3(64, 4), 256, 0, stream>>>(x, flag, ss1, 1);

    grn_x_kernel<<<2048, 256, 0, stream>>>(x, g1p, be1p, ss1, flag, Fc);
    transpose_kernel<<<dim3(160, 32), dim3(32, 8), 0, stream>>>(w_qkv, FqkvT, 1024, 5120, flag);
    gemm_bt_kernel<0, 128><<<dim3(40, 32), 256, 0, stream>>>(Fc, FqkvT, nullptr, nullptr, Fqkv, 5120, 1024, flag, nullptr);
    attn_kernel<<<dim3(16, 16, 4), 256, 0, stream>>>(Fqkv, lamp, Fc);
    transpose_kernel<<<dim3(32, 32), dim3(32, 8), 0, stream>>>(w_proj, FpT, 1024, 1024, flag);
    gemm_bt_kernel<1, 64><<<dim3(8, 64), 256, 0, stream>>>(Fc, FpT, bprojp, x, FX2, 1024, 1024, flag, ss2);
    grn_bf16_kernel<<<2048, 256, 0, stream>>>(FX2, g2p, be2p, ss2, Fc);
    transpose_kernel<<<dim3(128, 32), dim3(32, 8), 0, stream>>>(w1, FwT, 1024, 4096, flag);
    gemm_bt_kernel<2, 128><<<dim3(32, 32), 256, 0, stream>>>(Fc, FwT, b1p, nullptr, Fmid, 4096, 1024, flag, nullptr);
    transpose_kernel<<<dim3(32, 128), dim3(32, 8), 0, stream>>>(w2, FwT, 4096, 1024, flag);
    gemm_bt_kernel<3, 64><<<dim3(8, 64), 256, 0, stream>>>(Fmid, FwT, b2p, FX2, d_out, 1024, 4096, flag, nullptr);
}